// Round 10
// baseline (921.381 us; speedup 1.0000x reference)
//
#include <hip/hip_runtime.h>
#include <hip/hip_bf16.h>
#include <cstdint>

// Conformer block, MI355X gfx950. f32 in, f32 out, bf16 MFMA internals.
// Round 10: flash attention (fused S/softmax/PV, online softmax, QR-gather bias).

using bf16_t = __hip_bfloat16;
typedef __bf16 bf16x8 __attribute__((ext_vector_type(8)));
typedef float floatx4 __attribute__((ext_vector_type(4)));

struct alignas(16) hbf8 { bf16_t h[8]; };

__device__ __forceinline__ float  b2f(bf16_t h) { return __bfloat162float(h); }
__device__ __forceinline__ bf16_t f2b(float f)  { return __float2bfloat16(f); }
__device__ __forceinline__ float  sig_(float x) { return 1.f / (1.f + __expf(-x)); }

__device__ __forceinline__ void async16(const void* g, void* l) {
  __builtin_amdgcn_global_load_lds(
      (const __attribute__((address_space(1))) unsigned int*)(uintptr_t)g,
      (__attribute__((address_space(3))) unsigned int*)(uintptr_t)l, 16, 0, 0);
}

// ---------------------------------------------------------------- GEMM (MFMA)
// C[M,N] = A[M,K] @ Bt[N,K]^T ; EPI 0: bf16 = alpha*acc+bias ; 1: swish ; 2: resid += beta*(acc+bias)
struct GemmArgs {
  const bf16_t* A; const bf16_t* Bt; const float* bias;
  bf16_t* C; float* resid;
  int K, lda, ldb, ldc;
  float alpha, beta;
};

template <int BM, int BN, int WR, int WC, int EPI>
__global__ __launch_bounds__(256) void gemm_bt(GemmArgs g) {
  constexpr int FM = BM / (WR * 16);
  constexpr int FN = BN / (WC * 16);
  constexpr int IA = (BM * 4) / 256;
  constexpr int IB = (BN * 4) / 256;
  __shared__ __align__(16) bf16_t As[BM * 32];
  __shared__ __align__(16) bf16_t Bs[BN * 32];
  const int tid = threadIdx.x;
  const int lane = tid & 63, w = tid >> 6;
  const int bm0 = blockIdx.y * BM, bn0 = blockIdx.x * BN;
  const int wm0 = (w / WC) * (FM * 16);
  const int wn0 = (w % WC) * (FN * 16);
  const int lrow = lane & 15, lq = lane >> 4;

  floatx4 acc[FM][FN] = {};

  for (int k0 = 0; k0 < g.K; k0 += 32) {
#pragma unroll
    for (int i = 0; i < IA; ++i) {
      int c = i * 256 + tid;
      int m = c >> 2, kk = (c & 3) * 8;
      async16(g.A + (long)(bm0 + m) * g.lda + (k0 + kk), (char*)As + c * 16);
    }
#pragma unroll
    for (int i = 0; i < IB; ++i) {
      int c = i * 256 + tid;
      int n = bn0 + (c >> 2), kk = (c & 3) * 8;
      async16(g.Bt + (long)n * g.ldb + (k0 + kk), (char*)Bs + c * 16);
    }
    __syncthreads();
    bf16x8 af[FM], bfr[FN];
#pragma unroll
    for (int fm = 0; fm < FM; ++fm)
      af[fm] = *(const bf16x8*)(As + (wm0 + fm * 16 + lrow) * 32 + lq * 8);
#pragma unroll
    for (int fn = 0; fn < FN; ++fn)
      bfr[fn] = *(const bf16x8*)(Bs + (wn0 + fn * 16 + lrow) * 32 + lq * 8);
#pragma unroll
    for (int fm = 0; fm < FM; ++fm)
#pragma unroll
      for (int fn = 0; fn < FN; ++fn)
        acc[fm][fn] = __builtin_amdgcn_mfma_f32_16x16x32_bf16(af[fm], bfr[fn], acc[fm][fn], 0, 0, 0);
    __syncthreads();
  }

  const int bi = bm0 + wm0 + lq * 4;
  const int bj = bn0 + wn0 + lrow;
  if constexpr (EPI == 2) {
    float* R = g.resid;
#pragma unroll
    for (int fm = 0; fm < FM; ++fm)
#pragma unroll
      for (int fn = 0; fn < FN; ++fn) {
        int j = bj + fn * 16;
        float bv = g.bias ? g.bias[j] : 0.f;
#pragma unroll
        for (int r = 0; r < 4; ++r) {
          long i = bi + fm * 16 + r;
          R[i * g.ldc + j] += g.beta * (acc[fm][fn][r] + bv);
        }
      }
  } else {
    bf16_t* C = g.C;
#pragma unroll
    for (int fm = 0; fm < FM; ++fm)
#pragma unroll
      for (int fn = 0; fn < FN; ++fn) {
        int j = bj + fn * 16;
        float bv = g.bias ? g.bias[j] : 0.f;
#pragma unroll
        for (int r = 0; r < 4; ++r) {
          int i = bi + fm * 16 + r;
          float v = acc[fm][fn][r];
          if constexpr (EPI == 0) v = g.alpha * v + bv;
          if constexpr (EPI == 1) { v += bv; v = v * sig_(v); }
          C[(long)i * g.ldc + j] = f2b(v);
        }
      }
  }
}

// ---------------------------------------------------------------- flash attention
// grid (8 Q-tiles, NB*8 z). Per block: Q-tile 128 rows, loop K-tiles of 128:
// S = Qs@Ks^T + qr-gather bias -> online softmax -> P via LDS -> O += P@V (VT tiles).
__global__ __launch_bounds__(256) void flash_kernel(
    const bf16_t* __restrict__ Q, const bf16_t* __restrict__ KV,
    const bf16_t* __restrict__ VT, const bf16_t* __restrict__ QR,
    bf16_t* __restrict__ O) {
  __shared__ __align__(16) char smem[65536];
  bf16_t* Ks  = (bf16_t*)(smem);           // [128][64]
  bf16_t* VTs = (bf16_t*)(smem + 16384);   // [64][128]
  bf16_t* Ps  = (bf16_t*)(smem + 32768);   // [128][128]
  bf16_t* Qs  = (bf16_t*)(smem + 32768);   // alias (dead after afq load)

  const int tid = threadIdx.x;
  const int lane = tid & 63, w = tid >> 6;
  const int i0 = blockIdx.x * 128;
  const int zb = blockIdx.y >> 3, zh = blockIdx.y & 7;
  const int lrow = lane & 15, lq = lane >> 4;
  const int wm0 = w * 32;

  const bf16_t* Qbase = Q + (long)zb * 524288 + zh * 64;    // row stride 512
  const bf16_t* Kbase = KV + (long)zb * 1048576 + zh * 64;  // row stride 1024
  const bf16_t* VTz   = VT + (long)blockIdx.y * 65536;      // [d][j], ld 1024

  // stage Q tile
#pragma unroll
  for (int it = 0; it < 4; ++it) {
    int c = it * 256 + tid;
    int r = c >> 3, kc = c & 7;
    async16(Qbase + (long)(i0 + r) * 512 + kc * 8, (char*)Qs + c * 16);
  }
  __syncthreads();
  bf16x8 afq[2][2];
#pragma unroll
  for (int fm = 0; fm < 2; ++fm)
#pragma unroll
    for (int ks = 0; ks < 2; ++ks)
      afq[fm][ks] = *(const bf16x8*)(Qs + (wm0 + fm * 16 + lrow) * 64 + ks * 32 + lq * 8);

  floatx4 acc_o[2][4] = {};
  float mr[2][4], lr[2][4];
#pragma unroll
  for (int fm = 0; fm < 2; ++fm)
#pragma unroll
    for (int r = 0; r < 4; ++r) { mr[fm][r] = -1e30f; lr[fm][r] = 0.f; }

  for (int j0 = 0; j0 < 1024; j0 += 128) {
    __syncthreads();   // prev PV / afq reads done before overwriting LDS
#pragma unroll
    for (int it = 0; it < 4; ++it) {
      int c = it * 256 + tid;
      int r = c >> 3, kc = c & 7;
      async16(Kbase + (long)(j0 + r) * 1024 + kc * 8, (char*)Ks + c * 16);
    }
#pragma unroll
    for (int it = 0; it < 4; ++it) {
      int c = it * 256 + tid;
      int d = c >> 4, jc = c & 15;
      async16(VTz + (long)d * 1024 + j0 + jc * 8, (char*)VTs + c * 16);
    }
    __syncthreads();

    // S tile (per wave 32x128)
    floatx4 s[2][8] = {};
#pragma unroll
    for (int ks = 0; ks < 2; ++ks) {
      bf16x8 bk[8];
#pragma unroll
      for (int fn = 0; fn < 8; ++fn)
        bk[fn] = *(const bf16x8*)(Ks + (fn * 16 + lrow) * 64 + ks * 32 + lq * 8);
#pragma unroll
      for (int fm = 0; fm < 2; ++fm)
#pragma unroll
        for (int fn = 0; fn < 8; ++fn)
          s[fm][fn] = __builtin_amdgcn_mfma_f32_16x16x32_bf16(afq[fm][ks], bk[fn], s[fm][fn], 0, 0, 0);
    }
    // rel-pos bias gather (verified EPI3 indexing)
#pragma unroll
    for (int fm = 0; fm < 2; ++fm)
#pragma unroll
      for (int r = 0; r < 4; ++r) {
        int i = i0 + wm0 + fm * 16 + lq * 4 + r;
        const bf16_t* qrow = QR + (long)((zb * 1024 + i) * 8 + zh) * 1152;
#pragma unroll
        for (int fn = 0; fn < 8; ++fn) {
          int j = j0 + fn * 16 + lrow;
          int t = i - j; t = t < -512 ? -512 : (t > 512 ? 512 : t);
          s[fm][fn][r] += b2f(qrow[t + 512]);
        }
      }
    // online softmax per row (rows wave-private; 16-lane groups share a row)
#pragma unroll
    for (int fm = 0; fm < 2; ++fm)
#pragma unroll
      for (int r = 0; r < 4; ++r) {
        float mx = -1e30f;
#pragma unroll
        for (int fn = 0; fn < 8; ++fn) mx = fmaxf(mx, s[fm][fn][r]);
        for (int m = 1; m < 16; m <<= 1) mx = fmaxf(mx, __shfl_xor(mx, m));
        float mnew = fmaxf(mr[fm][r], mx);
        float alpha = __expf(mr[fm][r] - mnew);
        float sum = 0.f;
#pragma unroll
        for (int fn = 0; fn < 8; ++fn) {
          float e = __expf(s[fm][fn][r] - mnew);
          s[fm][fn][r] = e;
          sum += e;
        }
        for (int m = 1; m < 16; m <<= 1) sum += __shfl_xor(sum, m);
        lr[fm][r] = lr[fm][r] * alpha + sum;
        mr[fm][r] = mnew;
#pragma unroll
        for (int fn = 0; fn < 4; ++fn) acc_o[fm][fn][r] *= alpha;
      }
    // P -> LDS (C-layout -> row-major A-layout)
#pragma unroll
    for (int fm = 0; fm < 2; ++fm)
#pragma unroll
      for (int fn = 0; fn < 8; ++fn)
#pragma unroll
        for (int r = 0; r < 4; ++r)
          Ps[(wm0 + fm * 16 + lq * 4 + r) * 128 + fn * 16 + lrow] = f2b(s[fm][fn][r]);
    __syncthreads();
    // O += P @ V  (A = Ps rows, Bt = VTs rows)
#pragma unroll
    for (int ks = 0; ks < 4; ++ks) {
      bf16x8 ap[2], bv[4];
#pragma unroll
      for (int fm = 0; fm < 2; ++fm)
        ap[fm] = *(const bf16x8*)(Ps + (wm0 + fm * 16 + lrow) * 128 + ks * 32 + lq * 8);
#pragma unroll
      for (int fn = 0; fn < 4; ++fn)
        bv[fn] = *(const bf16x8*)(VTs + (fn * 16 + lrow) * 128 + ks * 32 + lq * 8);
#pragma unroll
      for (int fm = 0; fm < 2; ++fm)
#pragma unroll
        for (int fn = 0; fn < 4; ++fn)
          acc_o[fm][fn] = __builtin_amdgcn_mfma_f32_16x16x32_bf16(ap[fm], bv[fn], acc_o[fm][fn], 0, 0, 0);
    }
  }
  // epilogue: O[i, zh*64+d] = acc / l
  bf16_t* Ob = O + (long)zb * 524288 + zh * 64;
#pragma unroll
  for (int fm = 0; fm < 2; ++fm)
#pragma unroll
    for (int r = 0; r < 4; ++r) {
      int i = i0 + wm0 + fm * 16 + lq * 4 + r;
      float inv = 1.f / lr[fm][r];
#pragma unroll
      for (int fn = 0; fn < 4; ++fn)
        Ob[(long)i * 512 + fn * 16 + lrow] = f2b(acc_o[fm][fn][r] * inv);
    }
}

// ---------------------------------------------------------------- glue kernels
__global__ __launch_bounds__(256) void diag_kernel(float* __restrict__ out, long n, float v) {
  long i = (long)blockIdx.x * 256 + threadIdx.x;
  if (i < n) out[i] = v;
}

__global__ __launch_bounds__(256) void copy_kernel(const float* __restrict__ x, float* __restrict__ X) {
  long idx = ((long)blockIdx.x * 256 + threadIdx.x) * 4;
  *(float4*)(X + idx) = *(const float4*)(x + idx);
}

__global__ __launch_bounds__(256) void relpad_kernel(const float* __restrict__ rel, bf16_t* __restrict__ RELP) {
  int i = blockIdx.x * 256 + threadIdx.x;
  if (i < 73728) {
    int r = i >> 6, c = i & 63;
    RELP[i] = (r < 1025) ? f2b(rel[r * 64 + c]) : f2b(0.f);
  }
}

template <bool F32OUT>
__global__ __launch_bounds__(256) void ln_kernel(const float* __restrict__ X, const float* __restrict__ gam,
                                                 const float* __restrict__ bet, void* __restrict__ outv) {
  int row = blockIdx.x, tid = threadIdx.x;
  const float* x = X + (long)row * 512;
  float a = x[tid], b = x[tid + 256];
  float s = a + b, q = a * a + b * b;
  for (int off = 32; off; off >>= 1) { s += __shfl_down(s, off); q += __shfl_down(q, off); }
  __shared__ float red[8];
  int w = tid >> 6;
  if ((tid & 63) == 0) { red[w] = s; red[w + 4] = q; }
  __syncthreads();
  float ts = red[0] + red[1] + red[2] + red[3];
  float tq = red[4] + red[5] + red[6] + red[7];
  float mean = ts * (1.f / 512.f);
  float var = tq * (1.f / 512.f) - mean * mean;
  float rs = rsqrtf(var + 1e-5f);
  float o0 = (a - mean) * rs * gam[tid]       + bet[tid];
  float o1 = (b - mean) * rs * gam[tid + 256] + bet[tid + 256];
  if constexpr (F32OUT) {
    float* out = (float*)outv;
    out[(long)row * 512 + tid]       = o0;
    out[(long)row * 512 + tid + 256] = o1;
  } else {
    bf16_t* out = (bf16_t*)outv;
    out[(long)row * 512 + tid]       = f2b(o0);
    out[(long)row * 512 + tid + 256] = f2b(o1);
  }
}

__global__ __launch_bounds__(256) void transpose_kernel(const float* __restrict__ in, bf16_t* __restrict__ out,
                                                        int R, int C) {
  __shared__ float t[32][33];
  int c0 = blockIdx.x * 32, r0 = blockIdx.y * 32;
  int tx = threadIdx.x & 31, ty = threadIdx.x >> 5;
#pragma unroll
  for (int i = 0; i < 4; ++i)
    t[ty + i * 8][tx] = in[(long)(r0 + ty + i * 8) * C + c0 + tx];
  __syncthreads();
#pragma unroll
  for (int i = 0; i < 4; ++i)
    out[(long)(c0 + ty + i * 8) * R + r0 + tx] = f2b(t[tx][ty + i * 8]);
}

// VT[z=b*8+h][d][j] = KV[(b*1024+j)*1024 + 512 + h*64 + d]
__global__ __launch_bounds__(256) void vt_kernel(const bf16_t* __restrict__ KV, bf16_t* __restrict__ VT) {
  int jb = blockIdx.x, z = blockIdx.y;
  int b = z >> 3, h = z & 7;
  const bf16_t* src = KV + (long)b * 1024 * 1024 + 512 + h * 64;
  bf16_t* dst = VT + (long)z * 65536;
  __shared__ bf16_t t[64][65];
  int tid = threadIdx.x;
#pragma unroll
  for (int i = 0; i < 16; ++i) {
    int l = i * 256 + tid;
    int j = l >> 6, d = l & 63;
    t[d][j] = src[(long)(jb * 64 + j) * 1024 + d];
  }
  __syncthreads();
#pragma unroll
  for (int i = 0; i < 16; ++i) {
    int l = i * 256 + tid;
    int d = l >> 6, j = l & 63;
    dst[(long)d * 1024 + jb * 64 + j] = t[d][j];
  }
}

__global__ __launch_bounds__(256) void glu_kernel(const bf16_t* __restrict__ P, bf16_t* __restrict__ out) {
  long idx = ((long)blockIdx.x * 256 + threadIdx.x) * 8;
  long r = idx >> 10;
  int c = (int)(idx & 1023);
  hbf8 a = *(const hbf8*)(P + r * 2048 + c);
  hbf8 g = *(const hbf8*)(P + r * 2048 + 1024 + c);
  hbf8 o;
#pragma unroll
  for (int i = 0; i < 8; ++i) o.h[i] = f2b(b2f(a.h[i]) * sig_(b2f(g.h[i])));
  *(hbf8*)(out + idx) = o;
}

__global__ __launch_bounds__(256) void dwconv_kernel(const bf16_t* __restrict__ G, const float* __restrict__ dw,
    const float* __restrict__ db, const float* __restrict__ bng, const float* __restrict__ bnb,
    const float* __restrict__ bnm, const float* __restrict__ bnv, bf16_t* __restrict__ out) {
  int n0 = blockIdx.x * 32, c0 = blockIdx.y * 64, b = blockIdx.z;
  __shared__ bf16_t t[62][64];
  __shared__ float dws[31][64];
  int tid = threadIdx.x;
  const bf16_t* src = G + (long)b * 1024 * 1024 + c0;
#pragma unroll
  for (int i = 0; i < 16; ++i) {
    int l = i * 256 + tid;
    if (l < 3968) {
      int rr = l >> 6, c = l & 63;
      int n = n0 - 15 + rr;
      t[rr][c] = (n >= 0 && n < 1024) ? src[(long)n * 1024 + c] : f2b(0.f);
    }
  }
#pragma unroll
  for (int i = 0; i < 8; ++i) {
    int l = i * 256 + tid;
    if (l < 1984) {
      int k = l >> 6, c = l & 63;
      dws[k][c] = dw[(long)(c0 + c) * 31 + k];
    }
  }
  __syncthreads();
  int c = tid & 63, nl = tid >> 6;
  float rs = rsqrtf(bnv[c0 + c] + 1e-5f);
  float sc = rs * bng[c0 + c];
  float ab = (db[c0 + c] - bnm[c0 + c]) * sc + bnb[c0 + c];
#pragma unroll
  for (int j = 0; j < 8; ++j) {
    int rr = nl * 8 + j;
    float s = 0.f;
#pragma unroll
    for (int k = 0; k < 31; ++k) s += b2f(t[rr + k][c]) * dws[k][c];
    float y = s * sc + ab;
    out[((long)b * 1024 + n0 + rr) * 1024 + c0 + c] = f2b(y * sig_(y));
  }
}

// ---------------------------------------------------------------- launch
extern "C" void kernel_launch(void* const* d_in, const int* in_sizes, int n_in,
                              void* d_out, int out_size, void* d_ws, size_t ws_size,
                              hipStream_t stream) {
  auto fail = [&](float code) {
    diag_kernel<<<(out_size + 255) / 256, 256, 0, stream>>>((float*)d_out, out_size, code);
  };
  if (n_in != 34)             { fail(70.f);  return; }
  if (in_sizes[0] != 4194304) { fail(80.f);  return; }

  const float* x     = (const float*)d_in[0];
  const float* f1_g  = (const float*)d_in[1];
  const float* f1_b  = (const float*)d_in[2];
  const float* f1_w1 = (const float*)d_in[3];
  const float* f1_b1 = (const float*)d_in[4];
  const float* f1_w2 = (const float*)d_in[5];
  const float* f1_b2 = (const float*)d_in[6];
  const float* a_g   = (const float*)d_in[7];
  const float* a_b   = (const float*)d_in[8];
  const float* wq    = (const float*)d_in[9];
  const float* wkv   = (const float*)d_in[10];
  const float* wo    = (const float*)d_in[11];
  const float* wo_b  = (const float*)d_in[12];
  const float* rel   = (const float*)d_in[13];
  const float* c_g   = (const float*)d_in[14];
  const float* c_b   = (const float*)d_in[15];
  const float* cw1   = (const float*)d_in[16];
  const float* cb1   = (const float*)d_in[17];
  const float* dwp   = (const float*)d_in[18];
  const float* dbp   = (const float*)d_in[19];
  const float* bn_g  = (const float*)d_in[20];
  const float* bn_b  = (const float*)d_in[21];
  const float* bn_m  = (const float*)d_in[22];
  const float* bn_v  = (const float*)d_in[23];
  const float* cw2   = (const float*)d_in[24];
  const float* cb2   = (const float*)d_in[25];
  const float* f2_g  = (const float*)d_in[26];
  const float* f2_b  = (const float*)d_in[27];
  const float* f2_w1 = (const float*)d_in[28];
  const float* f2_b1 = (const float*)d_in[29];
  const float* f2_w2 = (const float*)d_in[30];
  const float* f2_b2 = (const float*)d_in[31];
  const float* p_g   = (const float*)d_in[32];
  const float* p_b   = (const float*)d_in[33];

  // ---- workspace arena ----
  // X 16.78M | WT 13.63M | D 33.55M {Q,KV,VT}/{GLU,DWO} | E: max(MID 33.55M, QR NB*18.87M) | RELP
  char* ws = (char*)d_ws;
  const size_t OFF_X  = 0;
  const size_t OFF_WT = 16777216;
  const size_t OFF_D  = 30408704;
  const size_t OFF_E  = 63963136;
  int NB = 1;
  {
    const int cands[3] = {8, 4, 2};
    for (int ci = 0; ci < 3; ++ci) {
      int nb = cands[ci];
      unsigned long long attn = (unsigned long long)nb * 18874368ULL;
      unsigned long long emax = attn > 33554432ULL ? attn : 33554432ULL;
      if (ws_size >= OFF_E + emax + 147456ULL) { NB = nb; break; }
    }
  }
  unsigned long long attn1 = (unsigned long long)NB * 18874368ULL;
  unsigned long long emax = attn1 > 33554432ULL ? attn1 : 33554432ULL;
  if (ws_size < OFF_E + emax + 147456ULL) { fail(200.f); return; }
  size_t relp_off = OFF_E + (size_t)emax;

  float*  X   = (float*)(ws + OFF_X);
  bf16_t* WT  = (bf16_t*)(ws + OFF_WT);
  bf16_t* Q   = (bf16_t*)(ws + OFF_D);
  bf16_t* KV  = (bf16_t*)(ws + OFF_D + 8388608);
  bf16_t* VT  = (bf16_t*)(ws + OFF_D + 25165824);
  bf16_t* GLU = (bf16_t*)(ws + OFF_D);
  bf16_t* DWO = (bf16_t*)(ws + OFF_D + 16777216);
  bf16_t* MID = (bf16_t*)(ws + OFF_E);
  bf16_t* QR  = (bf16_t*)(ws + OFF_E);             // chunk-local, overlays MID
  bf16_t* RELP= (bf16_t*)(ws + relp_off);
  bf16_t* H   = (bf16_t*)d_out;   // bf16 scratch inside f32 out buffer
  bf16_t* O   = (bf16_t*)d_out;   // final f32 LN overwrites at end

  bf16_t* f1_w1t = WT;            bf16_t* f1_w2t = WT + 1048576;
  bf16_t* wqt    = WT + 2097152;  bf16_t* wkvt   = WT + 2359296;
  bf16_t* wot    = WT + 2883584;  bf16_t* cw1t   = WT + 3145728;
  bf16_t* cw2t   = WT + 4194304;  bf16_t* f2_w1t = WT + 4718592;
  bf16_t* f2_w2t = WT + 5767168;

  auto GA = [](const bf16_t* A, const bf16_t* Bt, const float* bias, bf16_t* C,
               float* resid, int K, int lda, int ldb, int ldc, float alpha, float beta) {
    GemmArgs g{}; g.A = A; g.Bt = Bt; g.bias = bias; g.C = C; g.resid = resid;
    g.K = K; g.lda = lda; g.ldb = ldb; g.ldc = ldc; g.alpha = alpha; g.beta = beta;
    return g;
  };
  auto T = [&](const float* in, bf16_t* out, int R, int C) {
    transpose_kernel<<<dim3(C / 32, R / 32), 256, 0, stream>>>(in, out, R, C);
  };

  copy_kernel<<<4096, 256, 0, stream>>>(x, X);
  relpad_kernel<<<288, 256, 0, stream>>>(rel, RELP);
  T(f1_w1, f1_w1t, 512, 2048);  T(f1_w2, f1_w2t, 2048, 512);
  T(wq, wqt, 512, 512);         T(wkv, wkvt, 512, 1024);
  T(wo, wot, 512, 512);         T(cw1, cw1t, 512, 2048);
  T(cw2, cw2t, 1024, 512);      T(f2_w1, f2_w1t, 512, 2048);
  T(f2_w2, f2_w2t, 2048, 512);

  // ---- FF1 half-step ----
  ln_kernel<false><<<8192, 256, 0, stream>>>(X, f1_g, f1_b, H);
  { GemmArgs g = GA(H, f1_w1t, f1_b1, MID, nullptr, 512, 512, 512, 2048, 1.f, 0.f);
    gemm_bt<128, 128, 2, 2, 1><<<dim3(16, 64, 1), 256, 0, stream>>>(g); }
  { GemmArgs g = GA(MID, f1_w2t, f1_b2, nullptr, X, 2048, 2048, 2048, 512, 1.f, 0.5f);
    gemm_bt<64, 128, 1, 4, 2><<<dim3(4, 128, 1), 256, 0, stream>>>(g); }

  // ---- attention ----
  ln_kernel<false><<<8192, 256, 0, stream>>>(X, a_g, a_b, H);
  { GemmArgs g = GA(H, wqt, nullptr, Q, nullptr, 512, 512, 512, 512, 0.125f, 0.f);
    gemm_bt<128, 128, 2, 2, 0><<<dim3(4, 64, 1), 256, 0, stream>>>(g); }   // q (scale folded)
  { GemmArgs g = GA(H, wkvt, nullptr, KV, nullptr, 512, 512, 512, 1024, 1.f, 0.f);
    gemm_bt<128, 128, 2, 2, 0><<<dim3(8, 64, 1), 256, 0, stream>>>(g); }   // k|v
  vt_kernel<<<dim3(16, 64), 256, 0, stream>>>(KV, VT);

  for (int b0 = 0; b0 < 8; b0 += NB) {
    const bf16_t* Qc  = Q  + (long)b0 * 524288;
    const bf16_t* KVc = KV + (long)b0 * 1048576;
    // qr = q @ RELP^T, chunk view [NB*8192, 64] rows -> QR rows ((b*1024+i)*8+h)
    { GemmArgs g = GA(Qc, RELP, nullptr, QR, nullptr, 64, 64, 64, 1152, 1.f, 0.f);
      gemm_bt<128, 128, 2, 2, 0><<<dim3(9, NB * 64, 1), 256, 0, stream>>>(g); }
    flash_kernel<<<dim3(8, NB * 8), 256, 0, stream>>>(
        Qc, KVc, VT + (long)b0 * 524288, QR, O + (long)b0 * 524288);
  }
  { GemmArgs g = GA(O, wot, wo_b, nullptr, X, 512, 512, 512, 512, 1.f, 1.f);
    gemm_bt<64, 128, 1, 4, 2><<<dim3(4, 128, 1), 256, 0, stream>>>(g); }   // x += o@wo + b

  // ---- conv module ----
  ln_kernel<false><<<8192, 256, 0, stream>>>(X, c_g, c_b, H);
  { GemmArgs g = GA(H, cw1t, cb1, MID, nullptr, 512, 512, 512, 2048, 1.f, 0.f);
    gemm_bt<128, 128, 2, 2, 0><<<dim3(16, 64, 1), 256, 0, stream>>>(g); }  // pw1 + bias
  glu_kernel<<<4096, 256, 0, stream>>>(MID, GLU);
  dwconv_kernel<<<dim3(32, 16, 8), 256, 0, stream>>>(GLU, dwp, dbp, bn_g, bn_b, bn_m, bn_v, DWO);
  { GemmArgs g = GA(DWO, cw2t, cb2, nullptr, X, 1024, 1024, 1024, 512, 1.f, 1.f);
    gemm_bt<64, 128, 1, 4, 2><<<dim3(4, 128, 1), 256, 0, stream>>>(g); }   // x += h@cw2 + b

  // ---- FF2 half-step + post-LN (f32 out) ----
  ln_kernel<false><<<8192, 256, 0, stream>>>(X, f2_g, f2_b, H);
  { GemmArgs g = GA(H, f2_w1t, f2_b1, MID, nullptr, 512, 512, 512, 2048, 1.f, 0.f);
    gemm_bt<128, 128, 2, 2, 1><<<dim3(16, 64, 1), 256, 0, stream>>>(g); }
  { GemmArgs g = GA(MID, f2_w2t, f2_b2, nullptr, X, 2048, 2048, 2048, 512, 1.f, 0.5f);
    gemm_bt<64, 128, 1, 4, 2><<<dim3(4, 128, 1), 256, 0, stream>>>(g); }
  ln_kernel<true><<<8192, 256, 0, stream>>>(X, p_g, p_b, (float*)d_out);
}